// Round 1
// baseline (1914.622 us; speedup 1.0000x reference)
//
#include <hip/hip_runtime.h>
#include <math.h>

#define BB   128          // batch
#define SS   128          // seq
#define AHD  64
#define VHD  64
#define THD  128
#define AE   65           // AHD+1
#define VE   65
#define TE   129
#define KAV  (VE * TE)    // 8385 fused elems per 'a' slice
#define PFD  128
#define FUSED 545025UL    // AE*VE*TE
#define KSPAN 1024

// ---------------- zero-init accumulators ----------------
__global__ __launch_bounds__(256) void k_zero(float* __restrict__ p, int n) {
  int i = blockIdx.x * 256 + threadIdx.x;
  if (i < n) p[i] = 0.f;
}

// ---------------- phase A: fusion slice [b, a] -> F[b][al*KAV + v*TE + w] + normsq ----------------
// block = (b, a_local); 256 threads as (tv=tid>>4 [16], tw=tid&15 [16]); per-thread 5v x 9w tile
__global__ __launch_bounds__(256) void k_fusion(
    const float* __restrict__ audio, const float* __restrict__ vision,
    const float* __restrict__ text, float* __restrict__ F,
    float* __restrict__ normsq, int a_base, int Ga)
{
  const int b  = blockIdx.x;
  const int al = blockIdx.y;
  const int a  = a_base + al;
  const int tid = threadIdx.x;
  const int tw = tid & 15, tv = tid >> 4;

  __shared__ float sAcol[64];
  __shared__ float sSV[64][80];    // a-scaled extended vision, zero-padded v>=65
  __shared__ float sT[64][144];    // extended text, zero-padded w>=129

  float acc[5][9];
#pragma unroll
  for (int i = 0; i < 5; ++i)
#pragma unroll
    for (int j = 0; j < 9; ++j) acc[i][j] = 0.f;

  for (int sc = 0; sc < 2; ++sc) {   // two 64-deep s-chunks
    const int s0 = sc * 64;
    if (tid < 64) {
      const int s = s0 + tid;
      sAcol[tid] = (a == 0) ? 1.f : audio[((size_t)b * SS + s) * AHD + (a - 1)];
    }
#pragma unroll
    for (int r = 0; r < 36; ++r) {   // stage T: 64*144 elems
      const int e = tid + 256 * r;
      const int s = e / 144, w = e - s * 144;
      float val = 0.f;
      if (w < TE) val = (w == 0) ? 1.f : text[((size_t)b * SS + s0 + s) * THD + (w - 1)];
      sT[s][w] = val;
    }
    __syncthreads();
#pragma unroll
    for (int r = 0; r < 20; ++r) {   // stage SV = Acol[s] * v'[s][v]: 64*80 elems
      const int e = tid + 256 * r;
      const int s = e / 80, v = e - s * 80;
      float val = 0.f;
      if (v < VE) {
        const float vv = (v == 0) ? 1.f : vision[((size_t)b * SS + s0 + s) * VHD + (v - 1)];
        val = sAcol[s] * vv;
      }
      sSV[s][v] = val;
    }
    __syncthreads();
    for (int s = 0; s < 64; ++s) {   // rank-1 updates
      float sv[5], tt[9];
#pragma unroll
      for (int i = 0; i < 5; ++i) sv[i] = sSV[s][tv + 16 * i];
#pragma unroll
      for (int j = 0; j < 9; ++j) tt[j] = sT[s][tw + 16 * j];
#pragma unroll
      for (int i = 0; i < 5; ++i)
#pragma unroll
        for (int j = 0; j < 9; ++j) acc[i][j] += sv[i] * tt[j];
    }
    __syncthreads();
  }

  // write fusion slice (row-major per b within chunk) + accumulate ||fusion||^2
  const size_t Kc = (size_t)Ga * KAV;
  float* Fb = F + (size_t)b * Kc + (size_t)al * KAV;
  float ss = 0.f;
#pragma unroll
  for (int i = 0; i < 5; ++i) {
    const int v = tv + 16 * i;
    if (v < VE) {
#pragma unroll
      for (int j = 0; j < 9; ++j) {
        const int w = tw + 16 * j;
        if (w < TE) {
          const float m = acc[i][j];
          Fb[v * TE + w] = m;
          ss += m * m;
        }
      }
    }
  }
#pragma unroll
  for (int off = 32; off > 0; off >>= 1) ss += __shfl_down(ss, off);
  if ((tid & 63) == 0) atomicAdd(&normsq[b], ss);
}

// ---------------- phase B: y1pre[b][p] += W1[p][k] * F[b][k], K-split across blocks ----------------
// 256 threads as (tp=tid>>4, tb=tid&15); 8x8 register tile; LDS tiles transposed to [k][row]
__global__ __launch_bounds__(256) void k_gemm(
    const float* __restrict__ W1, const float* __restrict__ F,
    float* __restrict__ y1pre, int a_base, int Ga)
{
  const size_t Kc  = (size_t)Ga * KAV;
  const size_t kgb = (size_t)a_base * KAV;
  const size_t kc0 = (size_t)blockIdx.x * KSPAN;
  const int tid = threadIdx.x;
  const int tb = tid & 15, tp = tid >> 4;

  __shared__ float sW[32][132];   // [k][p]
  __shared__ float sF[32][132];   // [k][b]

  float acc[8][8];
#pragma unroll
  for (int i = 0; i < 8; ++i)
#pragma unroll
    for (int j = 0; j < 8; ++j) acc[i][j] = 0.f;

  for (int kt = 0; kt < KSPAN; kt += 32) {
    __syncthreads();
#pragma unroll
    for (int r = 0; r < 16; ++r) {   // stage 128 rows x 32 k for both operands
      const int e = tid + 256 * r;
      const int row = e >> 5, k = e & 31;
      const size_t kc = kc0 + kt + k;
      float wv = 0.f, fv = 0.f;
      if (kc < Kc) {
        wv = W1[(size_t)row * FUSED + kgb + kc];
        fv = F[(size_t)row * Kc + kc];
      }
      sW[k][row] = wv;
      sF[k][row] = fv;
    }
    __syncthreads();
#pragma unroll 4
    for (int k = 0; k < 32; ++k) {
      float wv[8], fv[8];
#pragma unroll
      for (int i = 0; i < 8; ++i) wv[i] = sW[k][tp * 8 + i];
#pragma unroll
      for (int j = 0; j < 8; ++j) fv[j] = sF[k][tb * 8 + j];
#pragma unroll
      for (int i = 0; i < 8; ++i)
#pragma unroll
        for (int j = 0; j < 8; ++j) acc[i][j] += wv[i] * fv[j];
    }
  }
#pragma unroll
  for (int i = 0; i < 8; ++i)
#pragma unroll
    for (int j = 0; j < 8; ++j)
      atomicAdd(&y1pre[(size_t)(tb * 8 + j) * PFD + (tp * 8 + i)], acc[i][j]);
}

// ---------------- finalize: MLP per batch ----------------
__global__ __launch_bounds__(128) void k_final(
    const float* __restrict__ y1pre, const float* __restrict__ b1,
    const float* __restrict__ W2, const float* __restrict__ b2,
    const float* __restrict__ W3, const float* __restrict__ b3,
    float* __restrict__ out)
{
  const int b = blockIdx.x, p = threadIdx.x;
  __shared__ float y1[PFD];
  __shared__ float red[PFD];
  y1[p] = fmaxf(y1pre[(size_t)b * PFD + p] + b1[p], 0.f);
  __syncthreads();
  float s = b2[p];
  for (int k = 0; k < PFD; ++k) s += y1[k] * W2[p * PFD + k];
  const float y2 = fmaxf(s, 0.f);
  red[p] = y2 * W3[p];
  __syncthreads();
  for (int off = 64; off > 0; off >>= 1) {
    if (p < off) red[p] += red[p + off];
    __syncthreads();
  }
  if (p == 0) {
    const float x = red[0] + b3[0];
    out[b] = 6.f / (1.f + expf(-x)) - 3.f;
  }
}

__global__ __launch_bounds__(128) void k_reg(const float* __restrict__ normsq,
                                             float* __restrict__ out)
{
  const int t = threadIdx.x;
  __shared__ float red[BB];
  red[t] = sqrtf(normsq[t]);
  __syncthreads();
  for (int off = 64; off > 0; off >>= 1) {
    if (t < off) red[t] += red[t + off];
    __syncthreads();
  }
  // tmp = sqrt(64*64*128/128) = 64 exactly; mean over B
  if (t == 0) out[BB] = 64.f * red[0] / (float)BB;
}

extern "C" void kernel_launch(void* const* d_in, const int* in_sizes, int n_in,
                              void* d_out, int out_size, void* d_ws, size_t ws_size,
                              hipStream_t stream) {
  const float* audio  = (const float*)d_in[0];
  const float* vision = (const float*)d_in[1];
  const float* text   = (const float*)d_in[2];
  const float* W1     = (const float*)d_in[3];
  const float* b1     = (const float*)d_in[4];
  const float* W2     = (const float*)d_in[5];
  const float* b2     = (const float*)d_in[6];
  const float* W3     = (const float*)d_in[7];
  const float* b3     = (const float*)d_in[8];
  float* out = (float*)d_out;

  // workspace layout: [y1pre 128*128][normsq 128] ... F at 128KB offset
  float* y1pre  = (float*)d_ws;
  float* normsq = y1pre + BB * PFD;
  const size_t reserved = 128 * 1024;
  float* F = (float*)((char*)d_ws + reserved);

  const size_t per_a = (size_t)BB * KAV * sizeof(float);  // 4,293,120 B per a-slice
  size_t avail = (ws_size > reserved) ? (ws_size - reserved) : 0;
  int Ga = (int)(avail / per_a);
  if (Ga > AE) Ga = AE;
  if (Ga < 1)  Ga = 1;   // assume ws is at least ~4.5 MB

  k_zero<<<65, 256, 0, stream>>>(y1pre, BB * PFD + BB);

  for (int ab = 0; ab < AE; ab += Ga) {
    const int g = (AE - ab < Ga) ? (AE - ab) : Ga;
    dim3 gridA(BB, g);
    k_fusion<<<gridA, 256, 0, stream>>>(audio, vision, text, F, normsq, ab, g);
    const size_t Kc = (size_t)g * KAV;
    const int nb = (int)((Kc + KSPAN - 1) / KSPAN);
    k_gemm<<<nb, 256, 0, stream>>>(W1, F, y1pre, ab, g);
  }

  k_final<<<BB, PFD, 0, stream>>>(y1pre, b1, W2, b2, W3, b3, out);
  k_reg<<<1, BB, 0, stream>>>(normsq, out);
}